// Round 5
// baseline (1249.666 us; speedup 1.0000x reference)
//
#include <hip/hip_runtime.h>

#define B 128
#define T 1500
#define NI 80        // N_MELS
#define H 128        // HIDDEN
#define G 384        // 3*H

typedef float v2f __attribute__((ext_vector_type(2)));

__device__ __forceinline__ float sigf(float x) { return 1.0f / (1.0f + __expf(-x)); }
__device__ __forceinline__ float tanhfast(float x) { return 1.0f - 2.0f / (1.0f + __expf(2.0f * x)); }
__device__ __forceinline__ v2f pkfma(v2f a, v2f b, v2f c) { return __builtin_elementwise_fma(a, b, c); }

// Fully fused: input projection + forward GRU scan + backward single step + MLP head.
// One block per batch element, 512 threads: tid = j*4 + q, j in [0,128), q in [0,4).
// Thread holds in VGPRs:
//   W_hh rows {j, j+H, j+2H}, k-slice [32q,32q+32)  (96 regs, packed v2f)
//   W_ih rows {j, j+H, j+2H}, i-slice [20q,20q+20)  (60 regs, float4)
//   x[b, t, 20q:20q+20] prefetched at distance 2    (2 x 5 float4)
// Per step: acc = W_hh·h_slice + W_ih·x_slice (78 pk_fma), quad butterfly reduce
// (xor1+xor2, DPP), gates, h write to LDS double buffer. Raw s_barrier with
// lgkmcnt-only wait keeps x prefetch loads in flight across barriers.
// n-gate needs x-part and h-part reduced separately (r multiplies only the h-part).
__global__ __launch_bounds__(512)
void fused_gru_kernel(const float* __restrict__ x,
                      const float* __restrict__ w_ih, const float* __restrict__ b_ih,
                      const float* __restrict__ w_hh, const float* __restrict__ b_hh,
                      const float* __restrict__ w_ih_b, const float* __restrict__ b_ih_b,
                      const float* __restrict__ b_hh_b,
                      const float* __restrict__ w1, const float* __restrict__ b1,
                      const float* __restrict__ w2, const float* __restrict__ b2,
                      float* __restrict__ out) {
    int b = blockIdx.x;
    int tid = threadIdx.x;
    int j = tid >> 2;
    int q = tid & 3;
    int jpad = j + ((j >> 5) << 2);   // padded h index (36-float q-slice stride)

    __shared__ __align__(16) float hs0[144];
    __shared__ __align__(16) float hs1[144];
    __shared__ __align__(16) float tail_gx[G];
    __shared__ __align__(16) float last_s[2 * H];
    __shared__ __align__(16) float xb_s[NI];

    // W_hh fragments (packed)
    v2f WR[16], WZ[16], WN[16];
    {
        const v2f* p0 = (const v2f*)(w_hh + (size_t)j * H + 32 * q);
        const v2f* p1 = (const v2f*)(w_hh + (size_t)(j + H) * H + 32 * q);
        const v2f* p2 = (const v2f*)(w_hh + (size_t)(j + 2 * H) * H + 32 * q);
#pragma unroll
        for (int i = 0; i < 16; ++i) { WR[i] = p0[i]; WZ[i] = p1[i]; WN[i] = p2[i]; }
    }
    // W_ih fragments (16B-aligned: (320j + 80q) % 16 == 0)
    float4 XWR[5], XWZ[5], XWN[5];
    {
        const float4* p0 = (const float4*)(w_ih + (size_t)j * NI + 20 * q);
        const float4* p1 = (const float4*)(w_ih + (size_t)(j + H) * NI + 20 * q);
        const float4* p2 = (const float4*)(w_ih + (size_t)(j + 2 * H) * NI + 20 * q);
#pragma unroll
        for (int i = 0; i < 5; ++i) { XWR[i] = p0[i]; XWZ[i] = p1[i]; XWN[i] = p2[i]; }
    }
    float brz = b_hh[j] ;             // h-part biases
    float bzz = b_hh[j + H];
    float bnh = b_hh[j + 2 * H];
    float cr = b_ih[j] + brz;         // merged bias for r (x-bias + h-bias)
    float cz = b_ih[j + H] + bzz;
    float cn = b_ih[j + 2 * H];       // x-part bias for n (kept separate)

    // x prefetch, distance 2: XA for even t, XB for odd t
    const float* xbase = x + (size_t)b * T * NI + 20 * q;
    float4 XA[5], XB[5];
#pragma unroll
    for (int i = 0; i < 5; ++i) XA[i] = *(const float4*)(xbase + i * 4);
#pragma unroll
    for (int i = 0; i < 5; ++i) XB[i] = *(const float4*)(xbase + NI + i * 4);

    float h_cur = 0.f;
    if (q == 0) hs0[jpad] = 0.f;
    __syncthreads();   // prologue only; vmcnt drain here is harmless

    auto step = [&](int TL, const float* SRC, float* DST, float4 (&XC)[5]) {
        const float4* hv4 = (const float4*)(SRC + 36 * q);
        v2f arv = {0.f, 0.f}, azv = {0.f, 0.f}, anh = {0.f, 0.f}, anx = {0.f, 0.f};
#pragma unroll
        for (int i = 0; i < 8; ++i) {
            float4 hv = hv4[i];
            v2f hlo = {hv.x, hv.y}, hhi = {hv.z, hv.w};
            arv = pkfma(WR[2 * i], hlo, arv);
            azv = pkfma(WZ[2 * i], hlo, azv);
            anh = pkfma(WN[2 * i], hlo, anh);
            arv = pkfma(WR[2 * i + 1], hhi, arv);
            azv = pkfma(WZ[2 * i + 1], hhi, azv);
            anh = pkfma(WN[2 * i + 1], hhi, anh);
        }
#pragma unroll
        for (int i = 0; i < 5; ++i) {
            float4 xv = XC[i];
            v2f xlo = {xv.x, xv.y}, xhi = {xv.z, xv.w};
            arv = pkfma(v2f{XWR[i].x, XWR[i].y}, xlo, arv);
            azv = pkfma(v2f{XWZ[i].x, XWZ[i].y}, xlo, azv);
            anx = pkfma(v2f{XWN[i].x, XWN[i].y}, xlo, anx);
            arv = pkfma(v2f{XWR[i].z, XWR[i].w}, xhi, arv);
            azv = pkfma(v2f{XWZ[i].z, XWZ[i].w}, xhi, azv);
            anx = pkfma(v2f{XWN[i].z, XWN[i].w}, xhi, anx);
        }
        // reload this register set for t+2 (clamped; loads stay in flight 2 steps)
        {
            int rt = TL + 2 < T ? TL + 2 : T - 1;
            const float* xp = xbase + (size_t)rt * NI;
#pragma unroll
            for (int i = 0; i < 5; ++i) XC[i] = *(const float4*)(xp + i * 4);
        }
        float ar = arv.x + arv.y, az = azv.x + azv.y;
        float ah = anh.x + anh.y, ax = anx.x + anx.y;
        ar += __shfl_xor(ar, 1); az += __shfl_xor(az, 1);
        ah += __shfl_xor(ah, 1); ax += __shfl_xor(ax, 1);
        ar += __shfl_xor(ar, 2); az += __shfl_xor(az, 2);
        ah += __shfl_xor(ah, 2); ax += __shfl_xor(ax, 2);
        float r = sigf(cr + ar);
        float z = sigf(cz + az);
        float n = tanhfast((cn + ax) + r * (bnh + ah));
        h_cur = (1.f - z) * n + z * h_cur;
        if (q == 0) DST[jpad] = h_cur;
        asm volatile("s_waitcnt lgkmcnt(0)\n\ts_barrier" ::: "memory");
    };

    for (int tl = 0; tl < T; tl += 2) {   // T even: no tail step
        step(tl,     hs0, hs1, XA);
        step(tl + 1, hs1, hs0, XB);
    }

    // ---- backward single step (h0 = 0) + MLP head ----
    if (tid < NI) xb_s[tid] = x[((size_t)b * T + (T - 1)) * NI + tid];
    if (q == 0) last_s[j] = h_cur;  // forward final hidden
    __syncthreads();

    if (tid < G) {
        const float4* wbr = (const float4*)(w_ih_b + (size_t)tid * NI);
        const float4* xv = (const float4*)xb_s;
        float a0 = 0.f, a1 = 0.f, a2 = 0.f, a3 = 0.f;
#pragma unroll
        for (int i = 0; i < 20; ++i) {
            float4 wv = wbr[i]; float4 x4 = xv[i];
            a0 = fmaf(wv.x, x4.x, a0); a1 = fmaf(wv.y, x4.y, a1);
            a2 = fmaf(wv.z, x4.z, a2); a3 = fmaf(wv.w, x4.w, a3);
        }
        tail_gx[tid] = b_ih_b[tid] + ((a0 + a1) + (a2 + a3));
    }
    __syncthreads();

    if (tid < H) {
        float r = sigf(tail_gx[tid] + b_hh_b[tid]);
        float z = sigf(tail_gx[tid + H] + b_hh_b[tid + H]);
        float n = tanhfast(tail_gx[tid + 2 * H] + r * b_hh_b[tid + 2 * H]);
        last_s[H + tid] = (1.f - z) * n;  // + z*0
    }
    __syncthreads();

    if (tid < 64) {
        const float4* w1r = (const float4*)(w1 + (size_t)tid * 2 * H);
        const float4* lv = (const float4*)last_s;
        float a0 = 0.f, a1 = 0.f, a2 = 0.f, a3 = 0.f;
#pragma unroll
        for (int i = 0; i < 64; ++i) {
            float4 wv = w1r[i]; float4 l4 = lv[i];
            a0 = fmaf(wv.x, l4.x, a0); a1 = fmaf(wv.y, l4.y, a1);
            a2 = fmaf(wv.z, l4.z, a2); a3 = fmaf(wv.w, l4.w, a3);
        }
        float v = b1[tid] + ((a0 + a1) + (a2 + a3));
        v = fmaxf(v, 0.f) * w2[tid];
#pragma unroll
        for (int off = 32; off > 0; off >>= 1) v += __shfl_down(v, off);
        if (tid == 0) out[b] = v + b2[0];
    }
}

extern "C" void kernel_launch(void* const* d_in, const int* in_sizes, int n_in,
                              void* d_out, int out_size, void* d_ws, size_t ws_size,
                              hipStream_t stream) {
    (void)in_sizes; (void)n_in; (void)out_size; (void)d_ws; (void)ws_size;
    const float* x      = (const float*)d_in[0];
    const float* w_ih_f = (const float*)d_in[1];
    const float* w_hh_f = (const float*)d_in[2];
    const float* b_ih_f = (const float*)d_in[3];
    const float* b_hh_f = (const float*)d_in[4];
    const float* w_ih_b = (const float*)d_in[5];
    const float* w_hh_b = (const float*)d_in[6];  // unused: h0=0 makes gh_b = b_hh_b
    const float* b_ih_b = (const float*)d_in[7];
    const float* b_hh_b = (const float*)d_in[8];
    const float* w1     = (const float*)d_in[9];
    const float* b1     = (const float*)d_in[10];
    const float* w2     = (const float*)d_in[11];
    const float* b2     = (const float*)d_in[12];
    (void)w_hh_b;
    float* out = (float*)d_out;

    fused_gru_kernel<<<dim3(B), dim3(512), 0, stream>>>(
        x, w_ih_f, b_ih_f, w_hh_f, b_hh_f,
        w_ih_b, b_ih_b, b_hh_b, w1, b1, w2, b2, out);
}